// Round 11
// baseline (590.793 us; speedup 1.0000x reference)
//
#include <hip/hip_runtime.h>
#include <math.h>

#define NTOK 32768
#define HDIM 1024
#define NEXP 64
#define NE   (NTOK * NEXP)
#define CAP  512
#define GTB  64      // gemm tile tokens
#define PTB  32      // post tile tokens
#define CK   64
#define XRS  68      // LDS row stride: bank offset 4 per row -> conflict-free
#define CAND 6144
#define QMAX 2048

__device__ __forceinline__ unsigned f2key(float f) {
  unsigned u = __float_as_uint(f);
  return (u & 0x80000000u) ? ~u : (u | 0x80000000u);
}
// Pure key-range coarsening: bin r holds keys with -R in [r, r+1); bin 64 =
// unassigned sentinel. Used consistently in histogram AND extraction, so
// selection is exact regardless of float-rounding at bin edges.
__device__ __forceinline__ int bin_of(unsigned k) {
  if (k & 0x80000000u) return 0;
  float f = __uint_as_float(~k);        // = -R > 0
  f = fminf(f, 64.5f);
  return (int)f;
}

__global__ void init_kernel(unsigned* cnt, float* sumP, unsigned* ghist) {
  int i = blockIdx.x * 256 + threadIdx.x;
  if (i < NEXP) { cnt[i] = 0u; sumP[i] = 0.f; }
  if (i < NEXP * NEXP) ghist[i] = 0u;
}

// R14: split (R11 structure) with post at 4x wave-parallelism.
// Ledger: total 538 = router 318 (gemm ~150 + post ~170) + tail 220 (every
// round). R13's 2-row ILP was null -> compiler already interleaves rows; post
// is latency-bound because the GRID caps waves (16 rows/wave -> 2048 waves =
// 8/CU). Fix: 4 rows/wave -> 8192 waves, ~16-24 resident/CU (LDS 12.7KB,
// VGPR ~84 permit it). gemm byte-identical to R11 (~150us known). select
// header scan parallelized (64 dependent L2 loads -> wave prefix+ballot).
// Diagnostic: with gemm ~150 on top, select appears in top-5 iff >150.
__global__ __launch_bounds__(256) void gemm_kernel(
    const float* __restrict__ x, const float* __restrict__ w,
    float* __restrict__ logits) {
  __shared__ float sm[(GTB + NEXP) * XRS];    // 34816 B
  const int tid  = threadIdx.x;
  const int wid  = tid >> 6, lane = tid & 63;
  const int tg   = lane >> 4;                 // 0..3 token sub-slot
  const int eg   = lane & 15;                 // 0..15 expert sub-slot
  const int t0   = blockIdx.x * GTB;
  float* xs  = sm;
  float* wsm = sm + GTB * XRS;

  float acc[4][4] = {};

  for (int hc = 0; hc < HDIM / CK; ++hc) {
    const int h0 = hc * CK;
#pragma unroll
    for (int r = 0; r < 4; ++r) {
      int idx = tid + r * 256;
      int row = idx >> 4, c4 = idx & 15;
      *(float4*)(xs + row * XRS + c4 * 4) =
          *(const float4*)(x + (size_t)(t0 + row) * HDIM + h0 + c4 * 4);
      *(float4*)(wsm + row * XRS + c4 * 4) =
          *(const float4*)(w + (size_t)row * HDIM + h0 + c4 * 4);
    }
    __syncthreads();
#pragma unroll
    for (int s = 0; s < 16; ++s) {
      const int k4 = s * 4;
      float4 xv[4], wv[4];
#pragma unroll
      for (int i = 0; i < 4; ++i)
        xv[i] = *(const float4*)(xs + (wid * 16 + i * 4 + tg) * XRS + k4);
#pragma unroll
      for (int j = 0; j < 4; ++j)
        wv[j] = *(const float4*)(wsm + (j * 16 + eg) * XRS + k4);
#pragma unroll
      for (int i = 0; i < 4; ++i)
#pragma unroll
        for (int j = 0; j < 4; ++j)
          acc[i][j] += xv[i].x * wv[j].x + xv[i].y * wv[j].y +
                       xv[i].z * wv[j].z + xv[i].w * wv[j].w;
    }
    __syncthreads();
  }

  // epilogue: registers -> global, no LDS round-trip.
#pragma unroll
  for (int i = 0; i < 4; ++i) {
    int tl = wid * 16 + i * 4 + tg;
#pragma unroll
    for (int j = 0; j < 4; ++j)
      logits[(size_t)(t0 + tl) * NEXP + j * 16 + eg] = acc[i][j];
  }
}

// post: verified row code, 512 threads = 8 waves x 4 rows -> 8192 waves
// grid-wide (4x prior), the latency-hiding the 16-rows/wave shape forbade.
// Logits in-place in probs buffer.
__global__ __launch_bounds__(512) void post_kernel(
    float* __restrict__ probs, unsigned* __restrict__ keyNE,
    unsigned* __restrict__ keyEN, unsigned long long* __restrict__ assignB,
    unsigned* __restrict__ cnt, float* __restrict__ sumP,
    unsigned* __restrict__ ghist, float* __restrict__ out) {
  __shared__ unsigned kt[PTB * 65];           // 8320 B keys
  __shared__ unsigned lhist[NEXP * 17];       // 4352 B: 4x u8 bins per u32
  const int tid  = threadIdx.x;
  const int wid  = tid >> 6, lane = tid & 63;
  const int t0   = blockIdx.x * PTB;

  for (int i = tid; i < NEXP * 17; i += 512) lhist[i] = 0u;
  __syncthreads();

  for (int i = 0; i < 4; ++i) {
    const int tl = wid * 4 + i;                   // wid 0..7 -> tl 0..31
    const int t  = t0 + tl;
    float l = probs[(size_t)t * NEXP + lane];     // logit (in-place buffer)
    float mx = l;
#pragma unroll
    for (int m = 32; m >= 1; m >>= 1) mx = fmaxf(mx, __shfl_xor(mx, m));
    float ex = expf(l - mx);
    float ssum = ex;
#pragma unroll
    for (int m = 32; m >= 1; m >>= 1) ssum += __shfl_xor(ssum, m);
    float p = ex / ssum;
    int rank = 0; float csum = p;
#pragma unroll
    for (int d = 1; d < 64; ++d) {
      float pj = __shfl_xor(p, d);
      int H = d; H |= H >> 1; H |= H >> 2; H |= H >> 4; H -= (H >> 1);
      bool jlt = (lane & H) != 0;                 // j = lane^d < lane
      bool gt = (pj > p) || (pj == p && jlt);
      rank += gt ? 1 : 0;
      csum += gt ? pj : 0.f;
    }
    int kc = (csum >= 0.9f) ? rank : 63;
#pragma unroll
    for (int m = 32; m >= 1; m >>= 1) kc = min(kc, __shfl_xor(kc, m));
    const bool assign = (rank <= kc);
    float R = assign ? (p - (float)(rank + 1)) : -1e9f;
    unsigned key = f2key(R);
    probs[(size_t)t * NEXP + lane] = p;
    keyNE[(size_t)t * NEXP + lane] = key;
    kt[tl * 65 + lane] = key;
    // 64 lanes -> 64 distinct expert rows: no same-address contention; byte
    // lane picked by bin&3 (counts <= PTB=32 fit u8)
    {
      int b = bin_of(key);
      atomicAdd(&lhist[lane * 17 + (b >> 2)], 1u << ((b & 3) * 8));
    }
    unsigned long long ab = __ballot(assign);
    if (lane == 0) assignB[t] = ab;
    if (rank == 0) {
      out[(size_t)2 * NE + 1 + t] = (float)lane;
      atomicAdd(&cnt[lane], 1u);
      atomicAdd(&sumP[lane], p);
    }
  }
  __syncthreads();
#pragma unroll
  for (int r = 0; r < 4; ++r) {
    int idx = tid + r * 512;                      // 2048 = 64e x 32tl
    int e = idx >> 5, tl = idx & 31;
    keyEN[(size_t)e * NTOK + t0 + tl] = kt[tl * 65 + e];
  }
  for (int idx = tid; idx < NEXP * NEXP; idx += 512) {  // merge nonzero bins
    int ee = idx >> 6, b = idx & 63;
    unsigned v = (lhist[ee * 17 + (b >> 2)] >> ((b & 3) * 8)) & 0xffu;
    if (v) atomicAdd(&ghist[idx], v);
  }
}

// One block per expert. Boundary bin via WAVE-PARALLEL prefix over the 64
// ghist bins (was: 64 serial dependent L2 loads on tid 0); then one
// extraction scan + exact (key desc, token asc) quadratic tie-cut, with
// byte-narrowing backstops for pathological bin populations.
__global__ __launch_bounds__(1024) void select_kernel(
    const unsigned* __restrict__ keyEN, const unsigned* __restrict__ ghist,
    unsigned* __restrict__ theta, int* __restrict__ tieCut) {
  const int e = blockIdx.x;
  const unsigned* col = keyEN + (size_t)e * NTOK;
  const int tid = threadIdx.x, wid = tid >> 6;
  __shared__ unsigned wh[16][256];
  __shared__ unsigned h[256];
  __shared__ unsigned cA_k[CAND], cA_t[CAND], cB_k[CAND], cB_t[CAND];
  __shared__ unsigned s_n, s_b;
  __shared__ int s_rb, s_need, s_cnt;
  __shared__ unsigned s_theta; __shared__ int s_cut;

  if (tid < 64) {                       // wave 0: parallel boundary-bin find
    unsigned c = ghist[e * 64 + tid];
    unsigned cum = c;
#pragma unroll
    for (int ofs = 1; ofs < 64; ofs <<= 1) {
      unsigned v = __shfl_up(cum, ofs);
      if (tid >= ofs) cum += v;
    }
    unsigned long long reach = __ballot(cum >= (unsigned)CAP);
    int rb = reach ? (__ffsll((long long)reach) - 1) : -1;
    if (tid == 0 && rb < 0) { s_rb = -1; s_need = 0; s_cnt = 0; }
    if (tid == rb) {                    // exactly one lane
      s_rb = rb; s_need = CAP - (int)(cum - c); s_cnt = (int)c;
    }
  }
  __syncthreads();
  if (s_rb < 0) {   // fewer than CAP assigned: keep all assigned
    if (tid == 0) { theta[e] = f2key(-1e9f); tieCut[e] = -1; }
    return;
  }
  const int rb = s_rb;
  int need = s_need, cnt = s_cnt;
  unsigned pmask = 0u, pval = 0u;
  int level = 0;

  while (cnt > CAND && level < 4) {   // global byte-narrowing (backstop)
    const int sh = 24 - 8 * level;
    for (int r = tid; r < 16 * 256; r += 1024) ((unsigned*)wh)[r] = 0u;
    __syncthreads();
    for (int t = tid; t < NTOK; t += 1024) {
      unsigned k = col[t];
      if (bin_of(k) == rb && (k & pmask) == pval)
        atomicAdd(&wh[wid][(k >> sh) & 255u], 1u);
    }
    __syncthreads();
    if (tid < 256) {
      unsigned s = 0;
      for (int wv = 0; wv < 16; ++wv) s += wh[wv][tid];
      h[tid] = s;
    }
    __syncthreads();
    if (tid == 0) {
      unsigned cum = 0;
      for (int d = 255; d >= 0; --d) {
        if (cum + h[d] >= (unsigned)need) {
          s_b = (unsigned)d; s_need = need - (int)cum; s_cnt = (int)h[d];
          break;
        }
        cum += h[d];
      }
    }
    __syncthreads();
    need = s_need; cnt = s_cnt;
    pmask |= (255u << sh); pval |= (s_b << sh);
    level++;
    __syncthreads();
  }

  if (cnt > CAND) {   // key fully determined == pval; tie purely on token idx
    int lo = 0, hi = NTOK - 1;
    while (lo < hi) {
      int mid = (lo + hi) >> 1;
      if (tid == 0) s_n = 0u;
      __syncthreads();
      for (int t = tid; t <= mid; t += 1024)
        if (col[t] == pval) atomicAdd(&s_n, 1u);
      __syncthreads();
      if ((int)s_n >= need) hi = mid; else lo = mid + 1;
      __syncthreads();
    }
    if (tid == 0) { theta[e] = pval; tieCut[e] = lo; }
    return;
  }

  if (tid == 0) s_n = 0u;
  __syncthreads();
  for (int t = tid; t < NTOK; t += 1024) {   // extraction scan
    unsigned k = col[t];
    if (bin_of(k) == rb && (k & pmask) == pval) {
      unsigned i = atomicAdd(&s_n, 1u);
      cA_k[i] = k; cA_t[i] = (unsigned)t;
    }
  }
  __syncthreads();
  unsigned* ck = cA_k; unsigned* ct = cA_t;
  unsigned* nk = cB_k; unsigned* nt2 = cB_t;

  while (cnt > QMAX && level < 4) {   // in-LDS byte-narrowing
    const int sh = 24 - 8 * level;
    for (int r = tid; r < 16 * 256; r += 1024) ((unsigned*)wh)[r] = 0u;
    __syncthreads();
    for (int i = tid; i < cnt; i += 1024)
      atomicAdd(&wh[wid][(ck[i] >> sh) & 255u], 1u);
    __syncthreads();
    if (tid < 256) {
      unsigned s = 0;
      for (int wv = 0; wv < 16; ++wv) s += wh[wv][tid];
      h[tid] = s;
    }
    __syncthreads();
    if (tid == 0) {
      unsigned cum = 0;
      for (int d = 255; d >= 0; --d) {
        if (cum + h[d] >= (unsigned)need) {
          s_b = (unsigned)d; s_need = need - (int)cum; s_cnt = (int)h[d];
          break;
        }
        cum += h[d];
      }
      s_n = 0u;
    }
    __syncthreads();
    for (int i = tid; i < cnt; i += 1024) {
      if (((ck[i] >> sh) & 255u) == s_b) {
        unsigned j = atomicAdd(&s_n, 1u);
        nk[j] = ck[i]; nt2[j] = ct[i];
      }
    }
    __syncthreads();
    { unsigned* t1 = ck; ck = nk; nk = t1; t1 = ct; ct = nt2; nt2 = t1; }
    need = s_need; cnt = s_cnt; level++;
    __syncthreads();
  }

  for (int i = tid; i < cnt; i += 1024) {   // exact: need-th in strict order
    unsigned ki = ck[i], ti = ct[i];
    int c = 0;
    for (int j = 0; j < cnt; ++j) {
      unsigned kj = ck[j], tj = ct[j];
      c += (kj > ki || (kj == ki && tj < ti)) ? 1 : 0;
    }
    if (c == need - 1) { s_theta = ki; s_cut = (int)ti; }
  }
  __syncthreads();
  if (tid == 0) { theta[e] = s_theta; tieCut[e] = s_cut; }
}

__global__ __launch_bounds__(256) void write_kernel(
    const float* __restrict__ probs, const unsigned* __restrict__ keyNE,
    const unsigned long long* __restrict__ assignB,
    const unsigned* __restrict__ theta, const int* __restrict__ tieCut,
    const unsigned* __restrict__ cnt, const float* __restrict__ sumP,
    float* __restrict__ out) {
  const int id = blockIdx.x * 256 + threadIdx.x;
  const int t = id >> 6, e = id & 63;
  unsigned k = keyNE[id];
  float p = probs[id];
  bool a = (assignB[t] >> e) & 1ull;
  unsigned th = theta[e];
  int cut = tieCut[e];
  bool keep = (k > th) || ((k == th) && (t <= cut));
  bool msk = a && keep;
  out[id] = msk ? 1.f : 0.f;
  out[(size_t)NE + id] = msk ? p : 0.f;
  if (blockIdx.x == 0 && threadIdx.x < 64) {
    int ee = threadIdx.x;
    float v = ((float)cnt[ee] / (float)NTOK) * (sumP[ee] / (float)NTOK);
#pragma unroll
    for (int m = 32; m >= 1; m >>= 1) v += __shfl_xor(v, m);
    if (ee == 0) out[(size_t)2 * NE] = (float)NEXP * v * 0.01f;
  }
}

extern "C" void kernel_launch(void* const* d_in, const int* in_sizes, int n_in,
                              void* d_out, int out_size, void* d_ws, size_t ws_size,
                              hipStream_t stream) {
  const float* x = (const float*)d_in[0];
  const float* w = (const float*)d_in[1];
  float* out = (float*)d_out;

  char* ws = (char*)d_ws;
  float* probs                 = (float*)ws;
  unsigned* keyNE              = (unsigned*)(probs + NE);
  unsigned* keyEN              = keyNE + NE;
  unsigned long long* assignB  = (unsigned long long*)(keyEN + NE);
  unsigned* cnt                = (unsigned*)(assignB + NTOK);
  float* sumP                  = (float*)(cnt + NEXP);
  unsigned* theta              = (unsigned*)(sumP + NEXP);
  int* tieCut                  = (int*)(theta + NEXP);
  unsigned* ghist              = (unsigned*)(tieCut + NEXP);

  init_kernel<<<16, 256, 0, stream>>>(cnt, sumP, ghist);
  gemm_kernel<<<NTOK / GTB, 256, 0, stream>>>(x, w, probs);
  post_kernel<<<NTOK / PTB, 512, 0, stream>>>(probs, keyNE, keyEN, assignB,
                                              cnt, sumP, ghist, out);
  select_kernel<<<NEXP, 1024, 0, stream>>>(keyEN, ghist, theta, tieCut);
  write_kernel<<<NE / 256, 256, 0, stream>>>(probs, keyNE, assignB, theta,
                                             tieCut, cnt, sumP, out);
}

// Round 12
// 484.205 us; speedup vs baseline: 1.2201x; 1.2201x over previous
//
#include <hip/hip_runtime.h>
#include <math.h>

#define NTOK 32768
#define HDIM 1024
#define NEXP 64
#define NE   (NTOK * NEXP)
#define CAP  512
#define TB   32
#define XST  80      // LDS bf16 row stride: 160 B (16B-aligned b128 rows)
#define CAND 6144
#define QMAX 2048

typedef float f32x4 __attribute__((ext_vector_type(4)));
typedef short bf16x8 __attribute__((ext_vector_type(8)));

__device__ __forceinline__ unsigned f2key(float f) {
  unsigned u = __float_as_uint(f);
  return (u & 0x80000000u) ? ~u : (u | 0x80000000u);
}
// Pure key-range coarsening: bin r holds keys with -R in [r, r+1); bin 64 =
// unassigned sentinel. Used consistently in histogram AND extraction, so
// selection is exact regardless of float-rounding at bin edges.
__device__ __forceinline__ int bin_of(unsigned k) {
  if (k & 0x80000000u) return 0;
  float f = __uint_as_float(~k);        // = -R > 0
  f = fminf(f, 64.5f);
  return (int)f;
}

// truncation split: x = hi + lo with |err| <~ 2^-16 |x| (drop lo*lo term)
__device__ __forceinline__ void split_bf16(float x, short& hi, short& lo) {
  unsigned u = __float_as_uint(x);
  hi = (short)(u >> 16);
  float hf = __uint_as_float(u & 0xFFFF0000u);
  float l = x - hf;                     // exact in fp32
  lo = (short)(__float_as_uint(l) >> 16);
}

// init: zero accumulators AND pre-split w into bf16 hi/lo (done once; saves
// every router block re-converting the shared 256 KB w matrix).
__global__ void init_kernel(unsigned* cnt, float* sumP, unsigned* ghist,
                            const float* __restrict__ w,
                            short* __restrict__ whi, short* __restrict__ wlo) {
  int i = blockIdx.x * 256 + threadIdx.x;       // 4096 threads
  if (i < NEXP) { cnt[i] = 0u; sumP[i] = 0.f; }
  if (i < NEXP * NEXP) ghist[i] = 0u;
  for (int j = i; j < NEXP * HDIM; j += 4096) {
    short h, l; split_bf16(w[j], h, l);
    whi[j] = h; wlo[j] = l;
  }
}

// R15 = R13 fused structure with the GEMM moved to MFMA (split-bf16 x3).
// Model reconciliation (R7-R14): every tiling/occupancy/ILP variant was null
// because the kernel is ISSUE-bound on fp32 v_fmac: 8192 FMA/lane x 2cyc =
// 65K cyc/SIMD == measured GEMM time; post ~60K cyc == measured. Cutting
// cycles requires the matrix pipe. No fp32 MFMA -> split-bf16 3-term:
// logit = xh*wh + xh*wl + xl*wh (mfma_f32_16x16x32_bf16, fp32 accumulate),
// |err| ~1e-5 abs vs the ~1e-6 reassociation error already tolerated.
// Structure: 256 thr / 4 waves; wave (mh,nh) owns a 16x32 output slab =
// 2 MFMA tiles; 16 K-chunks of 64; x split on the fly into LDS, w loaded
// pre-split (bf16) from global into LDS. C/D mapping (verified, m89/m91):
// col=lane&15, row=(lane>>4)*4+reg. Post/select/write: byte-identical R13.
__global__ __launch_bounds__(256) void router_kernel(
    const float* __restrict__ x, const short* __restrict__ whig,
    const short* __restrict__ wlog,
    float* __restrict__ probs, unsigned* __restrict__ keyNE,
    unsigned* __restrict__ keyEN, unsigned long long* __restrict__ assignB,
    unsigned* __restrict__ cnt, float* __restrict__ sumP,
    unsigned* __restrict__ ghist, float* __restrict__ out) {
  __shared__ int smemi[7680];                 // 30720 B staging / ls / kt
  __shared__ unsigned lhist[NEXP * 17];       // 4352 B: 4x u8 bins per u32
  short* xh = (short*)smemi;                  // [32][80]
  short* xl = xh + 32 * XST;                  // [32][80]
  short* wh = xl + 32 * XST;                  // [64][80]
  short* wl = wh + 64 * XST;                  // [64][80]
  const int tid  = threadIdx.x;
  const int wid  = tid >> 6, lane = tid & 63;
  const int mh   = wid >> 1, nh = wid & 1;    // wave's M-half / N-half
  const int t0   = blockIdx.x * TB;

  for (int i = tid; i < NEXP * 17; i += 256) lhist[i] = 0u;

  f32x4 acc0 = {0.f, 0.f, 0.f, 0.f};          // N-tile 0 (cols nh*32+0..15)
  f32x4 acc1 = {0.f, 0.f, 0.f, 0.f};          // N-tile 1 (cols nh*32+16..31)

  const int xrow = tid >> 3, xk8 = (tid & 7) * 8;    // x stage: 8 f32/thread
  const int wrow = tid >> 2, wk16 = (tid & 3) * 16;  // w stage: 16 bf16/thr/arr

  for (int hc = 0; hc < HDIM / 64; ++hc) {
    const int h0 = hc * 64;
    // ---- stage x: read 8 f32 (coalesced), split, write bf16x8 hi+lo
    {
      const float* xp = x + (size_t)(t0 + xrow) * HDIM + h0 + xk8;
      float4 v0 = *(const float4*)xp;
      float4 v1 = *(const float4*)(xp + 4);
      float f[8] = {v0.x, v0.y, v0.z, v0.w, v1.x, v1.y, v1.z, v1.w};
      bf16x8 vh, vl;
#pragma unroll
      for (int j = 0; j < 8; ++j) { short h, l; split_bf16(f[j], h, l); vh[j] = h; vl[j] = l; }
      *(bf16x8*)(xh + xrow * XST + xk8) = vh;
      *(bf16x8*)(xl + xrow * XST + xk8) = vl;
    }
    // ---- stage w: pre-split bf16 from global (L2-resident), 2x b128 each
    {
      const bf16x8* gh = (const bf16x8*)(whig + (size_t)wrow * HDIM + h0 + wk16);
      const bf16x8* gl = (const bf16x8*)(wlog + (size_t)wrow * HDIM + h0 + wk16);
      bf16x8 a = gh[0], b = gh[1], c = gl[0], d = gl[1];
      *(bf16x8*)(wh + wrow * XST + wk16)     = a;
      *(bf16x8*)(wh + wrow * XST + wk16 + 8) = b;
      *(bf16x8*)(wl + wrow * XST + wk16)     = c;
      *(bf16x8*)(wl + wrow * XST + wk16 + 8) = d;
    }
    __syncthreads();
    // ---- 2 K-steps of 32; per step: 6 frag reads + 6 MFMAs per wave
#pragma unroll
    for (int ks = 0; ks < 2; ++ks) {
      const int kb = ks * 32 + (lane >> 4) * 8;          // this lane's k-offset
      const int ar = mh * 16 + (lane & 15);              // A row (token)
      const int br = nh * 32 + (lane & 15);              // B row (expert), tile0
      bf16x8 ah = *(const bf16x8*)(xh + ar * XST + kb);
      bf16x8 al = *(const bf16x8*)(xl + ar * XST + kb);
      bf16x8 bh0 = *(const bf16x8*)(wh + br * XST + kb);
      bf16x8 bl0 = *(const bf16x8*)(wl + br * XST + kb);
      bf16x8 bh1 = *(const bf16x8*)(wh + (br + 16) * XST + kb);
      bf16x8 bl1 = *(const bf16x8*)(wl + (br + 16) * XST + kb);
      acc0 = __builtin_amdgcn_mfma_f32_16x16x32_bf16(ah, bh0, acc0, 0, 0, 0);
      acc0 = __builtin_amdgcn_mfma_f32_16x16x32_bf16(ah, bl0, acc0, 0, 0, 0);
      acc0 = __builtin_amdgcn_mfma_f32_16x16x32_bf16(al, bh0, acc0, 0, 0, 0);
      acc1 = __builtin_amdgcn_mfma_f32_16x16x32_bf16(ah, bh1, acc1, 0, 0, 0);
      acc1 = __builtin_amdgcn_mfma_f32_16x16x32_bf16(ah, bl1, acc1, 0, 0, 0);
      acc1 = __builtin_amdgcn_mfma_f32_16x16x32_bf16(al, bh1, acc1, 0, 0, 0);
    }
    __syncthreads();
  }

  // ---- epilogue: C/D mapping col=lane&15, row=(lane>>4)*4+reg (verified)
  float* ls = (float*)smemi;                      // [32][65] logits
  unsigned* kt = (unsigned*)smemi + TB * 65;      // [32][65] keys
#pragma unroll
  for (int r = 0; r < 4; ++r) {
    int tl = mh * 16 + (lane >> 4) * 4 + r;
    int e0 = nh * 32 + (lane & 15);
    ls[tl * 65 + e0]      = acc0[r];
    ls[tl * 65 + e0 + 16] = acc1[r];
  }
  __syncthreads();

  // ---- post phase: verified code, 2 rows per iteration (R13 verbatim) ----
  for (int i = 0; i < 8; i += 2) {
    const int tlA = wid * 8 + i, tlB = tlA + 1;   // wid 0..3 -> tl 0..31
    const int tA  = t0 + tlA,  tB  = t0 + tlB;
    float lA = ls[tlA * 65 + lane];
    float lB = ls[tlB * 65 + lane];
    float mxA = lA, mxB = lB;
#pragma unroll
    for (int m = 32; m >= 1; m >>= 1) {
      mxA = fmaxf(mxA, __shfl_xor(mxA, m));
      mxB = fmaxf(mxB, __shfl_xor(mxB, m));
    }
    float exA = expf(lA - mxA), exB = expf(lB - mxB);
    float ssA = exA, ssB = exB;
#pragma unroll
    for (int m = 32; m >= 1; m >>= 1) {
      ssA += __shfl_xor(ssA, m);
      ssB += __shfl_xor(ssB, m);
    }
    float pA = exA / ssA, pB = exB / ssB;
    int rkA = 0, rkB = 0; float csA = pA, csB = pB;
#pragma unroll
    for (int d = 1; d < 64; ++d) {
      float pjA = __shfl_xor(pA, d);
      float pjB = __shfl_xor(pB, d);
      int H = d; H |= H >> 1; H |= H >> 2; H |= H >> 4; H -= (H >> 1);
      bool jlt = (lane & H) != 0;                 // j = lane^d < lane
      bool gA = (pjA > pA) || (pjA == pA && jlt);
      bool gB = (pjB > pB) || (pjB == pB && jlt);
      rkA += gA ? 1 : 0; csA += gA ? pjA : 0.f;
      rkB += gB ? 1 : 0; csB += gB ? pjB : 0.f;
    }
    int kcA = (csA >= 0.9f) ? rkA : 63;
    int kcB = (csB >= 0.9f) ? rkB : 63;
#pragma unroll
    for (int m = 32; m >= 1; m >>= 1) {
      kcA = min(kcA, __shfl_xor(kcA, m));
      kcB = min(kcB, __shfl_xor(kcB, m));
    }
    const bool asA = (rkA <= kcA);
    const bool asB = (rkB <= kcB);
    float RA = asA ? (pA - (float)(rkA + 1)) : -1e9f;
    float RB = asB ? (pB - (float)(rkB + 1)) : -1e9f;
    unsigned keyA = f2key(RA), keyB = f2key(RB);
    probs[(size_t)tA * NEXP + lane] = pA;
    probs[(size_t)tB * NEXP + lane] = pB;
    keyNE[(size_t)tA * NEXP + lane] = keyA;
    keyNE[(size_t)tB * NEXP + lane] = keyB;
    kt[tlA * 65 + lane] = keyA;
    kt[tlB * 65 + lane] = keyB;
    {
      int bA = bin_of(keyA);
      atomicAdd(&lhist[lane * 17 + (bA >> 2)], 1u << ((bA & 3) * 8));
      int bB = bin_of(keyB);
      atomicAdd(&lhist[lane * 17 + (bB >> 2)], 1u << ((bB & 3) * 8));
    }
    unsigned long long abA = __ballot(asA);
    unsigned long long abB = __ballot(asB);
    if (lane == 0) { assignB[tA] = abA; assignB[tB] = abB; }
    if (rkA == 0) {
      out[(size_t)2 * NE + 1 + tA] = (float)lane;
      atomicAdd(&cnt[lane], 1u);
      atomicAdd(&sumP[lane], pA);
    }
    if (rkB == 0) {
      out[(size_t)2 * NE + 1 + tB] = (float)lane;
      atomicAdd(&cnt[lane], 1u);
      atomicAdd(&sumP[lane], pB);
    }
  }
  __syncthreads();
#pragma unroll
  for (int r = 0; r < 8; ++r) {
    int idx = tid + r * 256;                      // 2048 = 64e x 32tl
    int e = idx >> 5, tl = idx & 31;
    keyEN[(size_t)e * NTOK + t0 + tl] = kt[tl * 65 + e];
  }
  for (int idx = tid; idx < NEXP * NEXP; idx += 256) {  // merge nonzero bins
    int ee = idx >> 6, b = idx & 63;
    unsigned v = (lhist[ee * 17 + (b >> 2)] >> ((b & 3) * 8)) & 0xffu;
    if (v) atomicAdd(&ghist[idx], v);
  }
}

// One block per expert. Boundary bin comes precomputed from ghist; one
// extraction scan + exact (key desc, token asc) quadratic tie-cut, with
// byte-narrowing backstops for pathological bin populations.
__global__ __launch_bounds__(1024) void select_kernel(
    const unsigned* __restrict__ keyEN, const unsigned* __restrict__ ghist,
    unsigned* __restrict__ theta, int* __restrict__ tieCut) {
  const int e = blockIdx.x;
  const unsigned* col = keyEN + (size_t)e * NTOK;
  const int tid = threadIdx.x, wid = tid >> 6;
  __shared__ unsigned wh[16][256];
  __shared__ unsigned h[256];
  __shared__ unsigned cA_k[CAND], cA_t[CAND], cB_k[CAND], cB_t[CAND];
  __shared__ unsigned s_n, s_b;
  __shared__ int s_rb, s_need, s_cnt;
  __shared__ unsigned s_theta; __shared__ int s_cut;

  if (tid == 0) {
    unsigned run = 0; int rb = -1, need = 0, cc = 0;
    for (int r = 0; r < 64; ++r) {
      unsigned c = ghist[e * 64 + r];
      if (rb < 0 && run + c >= CAP) { rb = r; need = CAP - (int)run; cc = (int)c; }
      run += c;
    }
    s_rb = rb; s_need = need; s_cnt = cc;
  }
  __syncthreads();
  if (s_rb < 0) {   // fewer than CAP assigned: keep all assigned
    if (tid == 0) { theta[e] = f2key(-1e9f); tieCut[e] = -1; }
    return;
  }
  const int rb = s_rb;
  int need = s_need, cnt = s_cnt;
  unsigned pmask = 0u, pval = 0u;
  int level = 0;

  while (cnt > CAND && level < 4) {   // global byte-narrowing (backstop)
    const int sh = 24 - 8 * level;
    for (int r = tid; r < 16 * 256; r += 1024) ((unsigned*)wh)[r] = 0u;
    __syncthreads();
    for (int t = tid; t < NTOK; t += 1024) {
      unsigned k = col[t];
      if (bin_of(k) == rb && (k & pmask) == pval)
        atomicAdd(&wh[wid][(k >> sh) & 255u], 1u);
    }
    __syncthreads();
    if (tid < 256) {
      unsigned s = 0;
      for (int wv = 0; wv < 16; ++wv) s += wh[wv][tid];
      h[tid] = s;
    }
    __syncthreads();
    if (tid == 0) {
      unsigned cum = 0;
      for (int d = 255; d >= 0; --d) {
        if (cum + h[d] >= (unsigned)need) {
          s_b = (unsigned)d; s_need = need - (int)cum; s_cnt = (int)h[d];
          break;
        }
        cum += h[d];
      }
    }
    __syncthreads();
    need = s_need; cnt = s_cnt;
    pmask |= (255u << sh); pval |= (s_b << sh);
    level++;
    __syncthreads();
  }

  if (cnt > CAND) {   // key fully determined == pval; tie purely on token idx
    int lo = 0, hi = NTOK - 1;
    while (lo < hi) {
      int mid = (lo + hi) >> 1;
      if (tid == 0) s_n = 0u;
      __syncthreads();
      for (int t = tid; t <= mid; t += 1024)
        if (col[t] == pval) atomicAdd(&s_n, 1u);
      __syncthreads();
      if ((int)s_n >= need) hi = mid; else lo = mid + 1;
      __syncthreads();
    }
    if (tid == 0) { theta[e] = pval; tieCut[e] = lo; }
    return;
  }

  if (tid == 0) s_n = 0u;
  __syncthreads();
  for (int t = tid; t < NTOK; t += 1024) {   // extraction scan
    unsigned k = col[t];
    if (bin_of(k) == rb && (k & pmask) == pval) {
      unsigned i = atomicAdd(&s_n, 1u);
      cA_k[i] = k; cA_t[i] = (unsigned)t;
    }
  }
  __syncthreads();
  unsigned* ck = cA_k; unsigned* ct = cA_t;
  unsigned* nk = cB_k; unsigned* nt2 = cB_t;

  while (cnt > QMAX && level < 4) {   // in-LDS byte-narrowing
    const int sh = 24 - 8 * level;
    for (int r = tid; r < 16 * 256; r += 1024) ((unsigned*)wh)[r] = 0u;
    __syncthreads();
    for (int i = tid; i < cnt; i += 1024)
      atomicAdd(&wh[wid][(ck[i] >> sh) & 255u], 1u);
    __syncthreads();
    if (tid < 256) {
      unsigned s = 0;
      for (int wv = 0; wv < 16; ++wv) s += wh[wv][tid];
      h[tid] = s;
    }
    __syncthreads();
    if (tid == 0) {
      unsigned cum = 0;
      for (int d = 255; d >= 0; --d) {
        if (cum + h[d] >= (unsigned)need) {
          s_b = (unsigned)d; s_need = need - (int)cum; s_cnt = (int)h[d];
          break;
        }
        cum += h[d];
      }
      s_n = 0u;
    }
    __syncthreads();
    for (int i = tid; i < cnt; i += 1024) {
      if (((ck[i] >> sh) & 255u) == s_b) {
        unsigned j = atomicAdd(&s_n, 1u);
        nk[j] = ck[i]; nt2[j] = ct[i];
      }
    }
    __syncthreads();
    { unsigned* t1 = ck; ck = nk; nk = t1; t1 = ct; ct = nt2; nt2 = t1; }
    need = s_need; cnt = s_cnt; level++;
    __syncthreads();
  }

  for (int i = tid; i < cnt; i += 1024) {   // exact: need-th in strict order
    unsigned ki = ck[i], ti = ct[i];
    int c = 0;
    for (int j = 0; j < cnt; ++j) {
      unsigned kj = ck[j], tj = ct[j];
      c += (kj > ki || (kj == ki && tj < ti)) ? 1 : 0;
    }
    if (c == need - 1) { s_theta = ki; s_cut = (int)ti; }
  }
  __syncthreads();
  if (tid == 0) { theta[e] = s_theta; tieCut[e] = s_cut; }
}

__global__ __launch_bounds__(256) void write_kernel(
    const float* __restrict__ probs, const unsigned* __restrict__ keyNE,
    const unsigned long long* __restrict__ assignB,
    const unsigned* __restrict__ theta, const int* __restrict__ tieCut,
    const unsigned* __restrict__ cnt, const float* __restrict__ sumP,
    float* __restrict__ out) {
  const int id = blockIdx.x * 256 + threadIdx.x;
  const int t = id >> 6, e = id & 63;
  unsigned k = keyNE[id];
  float p = probs[id];
  bool a = (assignB[t] >> e) & 1ull;
  unsigned th = theta[e];
  int cut = tieCut[e];
  bool keep = (k > th) || ((k == th) && (t <= cut));
  bool msk = a && keep;
  out[id] = msk ? 1.f : 0.f;
  out[(size_t)NE + id] = msk ? p : 0.f;
  if (blockIdx.x == 0 && threadIdx.x < 64) {
    int ee = threadIdx.x;
    float v = ((float)cnt[ee] / (float)NTOK) * (sumP[ee] / (float)NTOK);
#pragma unroll
    for (int m = 32; m >= 1; m >>= 1) v += __shfl_xor(v, m);
    if (ee == 0) out[(size_t)2 * NE] = (float)NEXP * v * 0.01f;
  }
}

extern "C" void kernel_launch(void* const* d_in, const int* in_sizes, int n_in,
                              void* d_out, int out_size, void* d_ws, size_t ws_size,
                              hipStream_t stream) {
  const float* x = (const float*)d_in[0];
  const float* w = (const float*)d_in[1];
  float* out = (float*)d_out;

  char* ws = (char*)d_ws;
  float* probs                 = (float*)ws;
  unsigned* keyNE              = (unsigned*)(probs + NE);
  unsigned* keyEN              = keyNE + NE;
  unsigned long long* assignB  = (unsigned long long*)(keyEN + NE);
  unsigned* cnt                = (unsigned*)(assignB + NTOK);
  float* sumP                  = (float*)(cnt + NEXP);
  unsigned* theta              = (unsigned*)(sumP + NEXP);
  int* tieCut                  = (int*)(theta + NEXP);
  unsigned* ghist              = (unsigned*)(tieCut + NEXP);
  short* whi                   = (short*)(ghist + NEXP * NEXP);
  short* wlo                   = whi + NEXP * HDIM;

  init_kernel<<<16, 256, 0, stream>>>(cnt, sumP, ghist, w, whi, wlo);
  router_kernel<<<NTOK / TB, 256, 0, stream>>>(x, whi, wlo, probs, keyNE,
                                               keyEN, assignB, cnt, sumP,
                                               ghist, out);
  select_kernel<<<NEXP, 1024, 0, stream>>>(keyEN, ghist, theta, tieCut);
  write_kernel<<<NE / 256, 256, 0, stream>>>(probs, keyNE, assignB, theta,
                                             tieCut, cnt, sumP, out);
}